// Round 1
// baseline (1428.912 us; speedup 1.0000x reference)
//
#include <hip/hip_runtime.h>
#include <hip/hip_bf16.h>
#include <math.h>

#define N_NODES  50000
#define N_EDGES  800000
#define HID      128
#define OUT_DIM  40
#define N_LAYERS 4
#define N_GRAPHS 128
#define BN_EPS   1e-5f

// ---------------------------------------------------------------- CSR build
__global__ void k_count(const int* __restrict__ dst, int* __restrict__ counts) {
    int e = blockIdx.x * blockDim.x + threadIdx.x;
    if (e < N_EDGES) atomicAdd(&counts[dst[e]], 1);
}

__global__ __launch_bounds__(1024) void k_scan(const int* __restrict__ counts,
                                               int* __restrict__ offsets,
                                               int* __restrict__ cursor) {
    __shared__ int part[1024];
    const int n = N_NODES;
    int t = threadIdx.x;
    int chunk = (n + 1023) / 1024;            // 49
    int lo = t * chunk;
    int hi = min(lo + chunk, n);
    int s = 0;
    for (int i = lo; i < hi; i++) s += counts[i];
    part[t] = s;
    __syncthreads();
    for (int d = 1; d < 1024; d <<= 1) {
        int v = (t >= d) ? part[t - d] : 0;
        __syncthreads();
        part[t] += v;
        __syncthreads();
    }
    int run = (t == 0) ? 0 : part[t - 1];
    for (int i = lo; i < hi; i++) {
        offsets[i] = run;
        cursor[i]  = run;
        run += counts[i];
    }
    if (t == 1023) offsets[n] = part[1023];
}

__global__ void k_fill(const int* __restrict__ src, const int* __restrict__ dst,
                       int* __restrict__ cursor, int* __restrict__ csr) {
    int e = blockIdx.x * blockDim.x + threadIdx.x;
    if (e < N_EDGES) {
        int p = atomicAdd(&cursor[dst[e]], 1);
        csr[p] = src[e];
    }
}

// -------------------------------------------- aggregation: h0 = (1+eps)*x + sum_in x
__global__ __launch_bounds__(256) void k_agg(const float* __restrict__ x,
                                             const int* __restrict__ csr,
                                             const int* __restrict__ offsets,
                                             float* __restrict__ out,
                                             const float* __restrict__ eps_arr,
                                             int layer) {
    int wave = (blockIdx.x * blockDim.x + threadIdx.x) >> 6;
    int lane = threadIdx.x & 63;
    if (wave >= N_NODES) return;
    float scale = 1.0f + eps_arr[layer];
    int off = offsets[wave], end = offsets[wave + 1];
    const float* xr = x + (size_t)wave * HID;
    float a0 = scale * xr[lane];
    float a1 = scale * xr[lane + 64];
    for (int e = off; e < end; e++) {
        int s = csr[e];
        const float* xs = x + (size_t)s * HID;
        a0 += xs[lane];
        a1 += xs[lane + 64];
    }
    float* o = out + (size_t)wave * HID;
    o[lane] = a0;
    o[lane + 64] = a1;
}

// -------------------------------------------- GEMM: out = epilogue(A @ W + b)
// A: [N,128], W: [128,128] row-major. W in LDS (64KB); A rows in regs,
// broadcast via shfl. 4 nodes per wave, 2 cols per lane.
// mode 0: relu(acc+b);  mode 1: BN(relu(acc+b))
__global__ __launch_bounds__(256) void k_gemm(const float* __restrict__ A,
                                              const float* __restrict__ W,
                                              const float* __restrict__ bias,
                                              const float* __restrict__ gamma,
                                              const float* __restrict__ beta,
                                              const float* __restrict__ mean,
                                              const float* __restrict__ var,
                                              float* __restrict__ out,
                                              int N, int mode) {
    __shared__ float Wl[HID * HID];          // 64 KB
    int tid = threadIdx.x;
    {
        const float4* W4 = (const float4*)W;
        float4* Wl4 = (float4*)Wl;
#pragma unroll
        for (int i = 0; i < (HID * HID / 4) / 256; i++)
            Wl4[tid + i * 256] = W4[tid + i * 256];
    }
    __syncthreads();

    int lane = tid & 63;
    int waveId = blockIdx.x * (blockDim.x >> 6) + (tid >> 6);
    int nWaves = gridDim.x * (blockDim.x >> 6);

    float b0 = bias[lane], b1 = bias[lane + 64];
    float g0 = 0, g1 = 0, bt0 = 0, bt1 = 0, mn0 = 0, mn1 = 0, iv0 = 0, iv1 = 0;
    if (mode == 1) {
        g0 = gamma[lane];  g1 = gamma[lane + 64];
        bt0 = beta[lane];  bt1 = beta[lane + 64];
        mn0 = mean[lane];  mn1 = mean[lane + 64];
        iv0 = rsqrtf(var[lane] + BN_EPS);
        iv1 = rsqrtf(var[lane + 64] + BN_EPS);
    }

    int nTiles = (N + 3) >> 2;
    for (int tile = waveId; tile < nTiles; tile += nWaves) {
        int base = tile * 4;
        float ar[4][2];
#pragma unroll
        for (int i = 0; i < 4; i++) {
            int r = base + i;
            if (r < N) {
                const float* Ar = A + (size_t)r * HID;
                ar[i][0] = Ar[lane];
                ar[i][1] = Ar[lane + 64];
            } else {
                ar[i][0] = 0.0f;
                ar[i][1] = 0.0f;
            }
        }
        float acc[4][2] = {{0, 0}, {0, 0}, {0, 0}, {0, 0}};
#pragma unroll 4
        for (int k = 0; k < 64; k++) {
            float w0 = Wl[k * HID + lane];
            float w1 = Wl[k * HID + lane + 64];
#pragma unroll
            for (int i = 0; i < 4; i++) {
                float a = __shfl(ar[i][0], k, 64);
                acc[i][0] += a * w0;
                acc[i][1] += a * w1;
            }
        }
#pragma unroll 4
        for (int k = 0; k < 64; k++) {
            float w0 = Wl[(k + 64) * HID + lane];
            float w1 = Wl[(k + 64) * HID + lane + 64];
#pragma unroll
            for (int i = 0; i < 4; i++) {
                float a = __shfl(ar[i][1], k, 64);
                acc[i][0] += a * w0;
                acc[i][1] += a * w1;
            }
        }
#pragma unroll
        for (int i = 0; i < 4; i++) {
            int r = base + i;
            if (r < N) {
                float v0 = fmaxf(acc[i][0] + b0, 0.0f);
                float v1 = fmaxf(acc[i][1] + b1, 0.0f);
                if (mode == 1) {
                    v0 = g0 * (v0 - mn0) * iv0 + bt0;
                    v1 = g1 * (v1 - mn1) * iv1 + bt1;
                }
                out[(size_t)r * HID + lane]      = v0;
                out[(size_t)r * HID + lane + 64] = v1;
            }
        }
    }
}

// -------------------------------------------- mean pool per graph (batch sorted)
__global__ __launch_bounds__(128) void k_pool(const float* __restrict__ X,
                                              const int* __restrict__ batch,
                                              float* __restrict__ pooled) {
    int g = blockIdx.x;                      // 0..127
    int tid = threadIdx.x;                   // 128 threads (col)
    __shared__ int sh[2];
    if (tid < 2) {
        int target = g + tid;
        int lo = 0, hi = N_NODES;
        while (lo < hi) {
            int mid = (lo + hi) >> 1;
            if (batch[mid] < target) lo = mid + 1; else hi = mid;
        }
        sh[tid] = lo;
    }
    __syncthreads();
    int lo = sh[0], hi = sh[1];
    float s = 0.0f;
    for (int i = lo; i < hi; i++) s += X[(size_t)i * HID + tid];
    float cnt = (float)(hi - lo);
    pooled[g * HID + tid] = s / fmaxf(cnt, 1.0f);
}

// -------------------------------------------- head: logits + log_softmax
__global__ __launch_bounds__(64) void k_final(const float* __restrict__ Hp,
                                              const float* __restrict__ W2,
                                              const float* __restrict__ b2,
                                              float* __restrict__ out) {
    int g = blockIdx.x;
    int lane = threadIdx.x;                  // 64 threads (one wave)
    __shared__ float h[HID];
    h[lane]      = Hp[g * HID + lane];
    h[lane + 64] = Hp[g * HID + lane + 64];
    __syncthreads();
    float acc = 0.0f;
    if (lane < OUT_DIM) {
        for (int k = 0; k < HID; k++) acc += h[k] * W2[k * OUT_DIM + lane];
        acc += b2[lane];
    }
    float v = (lane < OUT_DIM) ? acc : -INFINITY;
    for (int d = 32; d > 0; d >>= 1) v = fmaxf(v, __shfl_xor(v, d, 64));
    float ex = (lane < OUT_DIM) ? expf(acc - v) : 0.0f;
    float s = ex;
    for (int d = 32; d > 0; d >>= 1) s += __shfl_xor(s, d, 64);
    if (lane < OUT_DIM) out[g * OUT_DIM + lane] = acc - v - logf(s);
}

// ----------------------------------------------------------------- launcher
extern "C" void kernel_launch(void* const* d_in, const int* in_sizes, int n_in,
                              void* d_out, int out_size, void* d_ws, size_t ws_size,
                              hipStream_t stream) {
    const float* x       = (const float*)d_in[0];
    const int*   edge    = (const int*)d_in[1];
    const int*   batch   = (const int*)d_in[2];
    const float* W1s     = (const float*)d_in[3];
    const float* b1s     = (const float*)d_in[4];
    const float* W2s     = (const float*)d_in[5];
    const float* b2s     = (const float*)d_in[6];
    const float* gammas  = (const float*)d_in[7];
    const float* betas   = (const float*)d_in[8];
    const float* bn_m    = (const float*)d_in[9];
    const float* bn_v    = (const float*)d_in[10];
    const float* eps_arr = (const float*)d_in[11];
    const float* lin1_W  = (const float*)d_in[12];
    const float* lin1_b  = (const float*)d_in[13];
    const float* lin2_W  = (const float*)d_in[14];
    const float* lin2_b  = (const float*)d_in[15];

    const int* src = edge;
    const int* dst = edge + N_EDGES;

    // workspace layout (all 16B aligned by construction)
    float* bufA    = (float*)d_ws;                       // 50000*128 f32
    float* bufB    = bufA + (size_t)N_NODES * HID;       // 50000*128 f32
    int*   counts  = (int*)(bufB + (size_t)N_NODES * HID);   // 50000
    int*   offsets = counts + N_NODES;                   // 50004 (padded)
    int*   cursor  = offsets + N_NODES + 4;              // 50000
    int*   csr     = cursor + N_NODES;                   // 800000
    float* pooled  = (float*)(csr + N_EDGES);            // 128*128
    float* pooledH = pooled + N_GRAPHS * HID;            // 128*128

    // ---- CSR build (per call; inputs restored each call)
    hipMemsetAsync(counts, 0, N_NODES * sizeof(int), stream);
    k_count<<<(N_EDGES + 255) / 256, 256, 0, stream>>>(dst, counts);
    k_scan<<<1, 1024, 0, stream>>>(counts, offsets, cursor);
    k_fill<<<(N_EDGES + 255) / 256, 256, 0, stream>>>(src, dst, cursor, csr);

    // ---- GIN layers
    const float* cur = x;
    float* t0 = bufA;
    float* t1 = bufB;
    for (int l = 0; l < N_LAYERS; l++) {
        k_agg<<<(N_NODES * 64 + 255) / 256, 256, 0, stream>>>(cur, csr, offsets, t0, eps_arr, l);
        k_gemm<<<512, 256, 0, stream>>>(t0, W1s + (size_t)l * HID * HID, b1s + l * HID,
                                        nullptr, nullptr, nullptr, nullptr,
                                        t1, N_NODES, 0);
        k_gemm<<<512, 256, 0, stream>>>(t1, W2s + (size_t)l * HID * HID, b2s + l * HID,
                                        gammas + l * HID, betas + l * HID,
                                        bn_m + l * HID, bn_v + l * HID,
                                        t0, N_NODES, 1);
        cur = t0;
        float* tmp = t0; t0 = t1; t1 = tmp;
    }

    // ---- pool + head
    k_pool<<<N_GRAPHS, 128, 0, stream>>>(cur, batch, pooled);
    k_gemm<<<64, 256, 0, stream>>>(pooled, lin1_W, lin1_b,
                                   nullptr, nullptr, nullptr, nullptr,
                                   pooledH, N_GRAPHS, 0);
    k_final<<<N_GRAPHS, 64, 0, stream>>>(pooledH, lin2_W, lin2_b, (float*)d_out);
}

// Round 2
// 645.414 us; speedup vs baseline: 2.2139x; 2.2139x over previous
//
#include <hip/hip_runtime.h>
#include <hip/hip_bf16.h>
#include <math.h>

#define N_NODES  50000
#define N_EDGES  800000
#define HID      128
#define OUT_DIM  40
#define N_LAYERS 4
#define N_GRAPHS 128
#define BN_EPS   1e-5f
#define SCAN_BLKS 196   // ceil(50000/256)

typedef short v8s __attribute__((ext_vector_type(8)));
typedef float v4f __attribute__((ext_vector_type(4)));

static __device__ __forceinline__ short f2bf(float f) {
    __hip_bfloat16 h = __float2bfloat16(f);
    return __builtin_bit_cast(short, h);
}
static __device__ __forceinline__ float bflo(unsigned u) {   // low bf16 of packed pair
    return __builtin_bit_cast(float, u << 16);
}
static __device__ __forceinline__ float bfhi(unsigned u) {   // high bf16 of packed pair
    return __builtin_bit_cast(float, u & 0xffff0000u);
}

// ---------------------------------------------------------------- CSR build
__global__ void k_count(const int* __restrict__ dst, int* __restrict__ counts) {
    int e = blockIdx.x * blockDim.x + threadIdx.x;
    if (e < N_EDGES) atomicAdd(&counts[dst[e]], 1);
}

__global__ __launch_bounds__(256) void k_red(const int* __restrict__ counts,
                                             int* __restrict__ bsum) {
    int i = blockIdx.x * 256 + threadIdx.x;
    int v = (i < N_NODES) ? counts[i] : 0;
    for (int d = 32; d > 0; d >>= 1) v += __shfl_down(v, d, 64);
    __shared__ int sh[4];
    if ((threadIdx.x & 63) == 0) sh[threadIdx.x >> 6] = v;
    __syncthreads();
    if (threadIdx.x == 0) bsum[blockIdx.x] = sh[0] + sh[1] + sh[2] + sh[3];
}

__global__ __launch_bounds__(256) void k_scanB(const int* __restrict__ bsum,
                                               int* __restrict__ boff,
                                               int* __restrict__ offsets) {
    __shared__ int sh[256];
    int t = threadIdx.x;
    int v = (t < SCAN_BLKS) ? bsum[t] : 0;
    sh[t] = v;
    __syncthreads();
    for (int d = 1; d < 256; d <<= 1) {
        int u = (t >= d) ? sh[t - d] : 0;
        __syncthreads();
        sh[t] += u;
        __syncthreads();
    }
    boff[t] = (t == 0) ? 0 : sh[t - 1];
    if (t == 255) offsets[N_NODES] = sh[255];
}

__global__ __launch_bounds__(256) void k_scan3(const int* __restrict__ counts,
                                               const int* __restrict__ boff,
                                               int* __restrict__ offsets,
                                               int* __restrict__ cursor) {
    __shared__ int sh[256];
    int t = threadIdx.x;
    int i = blockIdx.x * 256 + t;
    int c = (i < N_NODES) ? counts[i] : 0;
    sh[t] = c;
    __syncthreads();
    for (int d = 1; d < 256; d <<= 1) {
        int u = (t >= d) ? sh[t - d] : 0;
        __syncthreads();
        sh[t] += u;
        __syncthreads();
    }
    int excl = sh[t] - c + boff[blockIdx.x];
    if (i < N_NODES) { offsets[i] = excl; cursor[i] = excl; }
}

__global__ void k_fill(const int* __restrict__ src, const int* __restrict__ dst,
                       int* __restrict__ cursor, int* __restrict__ csr) {
    int e = blockIdx.x * blockDim.x + threadIdx.x;
    if (e < N_EDGES) {
        int p = atomicAdd(&cursor[dst[e]], 1);
        csr[p] = src[e];
    }
}

// --------------------------------------- weight prep: fp32 [K][N] -> bf16 frag-packed
// frag f = ks*8+nt (32 frags); chunk(f,lane) = 8 bf16 = B[k=ks*32+(lane>>4)*8+j][n=nt*16+(lane&15)]
__global__ __launch_bounds__(256) void k_prep(const float* __restrict__ W1s,
                                              const float* __restrict__ W2s,
                                              const float* __restrict__ lin1,
                                              short* __restrict__ Wp) {
    int b = blockIdx.x;   // 0..8
    const float* W = (b < 4) ? (W1s + b * 16384)
                   : (b < 8) ? (W2s + (b - 4) * 16384)
                             : lin1;
    short* o = Wp + (size_t)b * 16384;
    int t = threadIdx.x;
#pragma unroll
    for (int i = 0; i < 8; i++) {
        int c = i * 256 + t;            // chunk 0..2047
        int f = c >> 6, lane = c & 63;
        int ks = f >> 3, nt = f & 7;
        int k0 = ks * 32 + (lane >> 4) * 8;
        int n  = nt * 16 + (lane & 15);
        union { v8s v; short s[8]; } u;
#pragma unroll
        for (int j = 0; j < 8; j++) u.s[j] = f2bf(W[(k0 + j) * 128 + n]);
        *(v8s*)(o + (size_t)c * 8) = u.v;
    }
}

// --------------------------------------------- aggregation (layer 0: fp32 input)
__global__ __launch_bounds__(256) void k_agg_f32(const float* __restrict__ x,
                                                 const int* __restrict__ csr,
                                                 const int* __restrict__ off,
                                                 short* __restrict__ outb,
                                                 const float* __restrict__ eps_arr,
                                                 int layer) {
    int wid = (blockIdx.x * 256 + threadIdx.x) >> 6;
    int lane = threadIdx.x & 63;
    if (wid >= N_NODES) return;
    float sc = 1.0f + eps_arr[layer];
    int e0 = off[wid], e1 = off[wid + 1];
    float2 v = ((const float2*)(x + (size_t)wid * HID))[lane];
    float a0 = sc * v.x, a1 = sc * v.y;
    for (int e = e0; e < e1; e++) {
        float2 u = ((const float2*)(x + (size_t)csr[e] * HID))[lane];
        a0 += u.x; a1 += u.y;
    }
    unsigned pk = ((unsigned)(unsigned short)f2bf(a1) << 16) | (unsigned short)f2bf(a0);
    ((unsigned*)outb)[(size_t)wid * 64 + lane] = pk;
}

// --------------------------------------------- aggregation (layers 1..3: bf16 input)
__global__ __launch_bounds__(256) void k_agg_b16(const short* __restrict__ xb,
                                                 const int* __restrict__ csr,
                                                 const int* __restrict__ off,
                                                 short* __restrict__ outb,
                                                 const float* __restrict__ eps_arr,
                                                 int layer) {
    int wid = (blockIdx.x * 256 + threadIdx.x) >> 6;
    int lane = threadIdx.x & 63;
    if (wid >= N_NODES) return;
    float sc = 1.0f + eps_arr[layer];
    int e0 = off[wid], e1 = off[wid + 1];
    const unsigned* X = (const unsigned*)xb;
    unsigned su = X[(size_t)wid * 64 + lane];
    float a0 = sc * bflo(su), a1 = sc * bfhi(su);
    for (int e = e0; e < e1; e++) {
        unsigned u = X[(size_t)csr[e] * 64 + lane];
        a0 += bflo(u);
        a1 += bfhi(u);
    }
    unsigned pk = ((unsigned)(unsigned short)f2bf(a1) << 16) | (unsigned short)f2bf(a0);
    ((unsigned*)outb)[(size_t)wid * 64 + lane] = pk;
}

// --------------------------------------------- MFMA GEMM: out = epi(A[N,128] @ W + b)
// block = 256 thr (4 waves): wave w: rows [blk*128 + (w>>1)*64, +64), cols [(w&1)*64, +64)
// mode 0: relu(y+b); mode 1: s*relu(y+b)+t (fused BN affine)
__global__ __launch_bounds__(256) void k_mm(const short* __restrict__ A,
                                            const short* __restrict__ Wp,
                                            const float* __restrict__ bias,
                                            const float* __restrict__ gamma,
                                            const float* __restrict__ beta,
                                            const float* __restrict__ mean,
                                            const float* __restrict__ var,
                                            short* __restrict__ out,
                                            int N, int mode) {
    __shared__ short Wl[16384];           // 32 KB, frag-packed
    int tid = threadIdx.x;
    {
        const v8s* s = (const v8s*)Wp;
        v8s* d = (v8s*)Wl;
#pragma unroll
        for (int i = 0; i < 8; i++) d[tid + i * 256] = s[tid + i * 256];
    }
    __syncthreads();

    int lane = tid & 63, w = tid >> 6;
    int m16 = lane & 15, quad = lane >> 4;
    int nh = w & 1, mh = w >> 1;
    int base = blockIdx.x * 128 + mh * 64;

    float pb[4], ps[4], pt[4];
#pragma unroll
    for (int nt = 0; nt < 4; nt++) {
        int c = nh * 64 + nt * 16 + m16;
        pb[nt] = bias[c];
        if (mode) {
            float g = gamma[c];
            float iv = rsqrtf(var[c] + BN_EPS);
            ps[nt] = g * iv;
            pt[nt] = beta[c] - g * mean[c] * iv;
        }
    }

    const v8s* Bl = (const v8s*)Wl;
    const v8s* Ap[4];
#pragma unroll
    for (int mt = 0; mt < 4; mt++) {
        int r = base + mt * 16 + m16;
        if (r >= N) r = 0;                       // clamp: rows >= N never stored
        Ap[mt] = (const v8s*)(A + (size_t)r * HID);
    }

    v4f acc[4][4];
#pragma unroll
    for (int mt = 0; mt < 4; mt++)
#pragma unroll
        for (int nt = 0; nt < 4; nt++) acc[mt][nt] = {0.f, 0.f, 0.f, 0.f};

#pragma unroll
    for (int ks = 0; ks < 4; ks++) {
        v8s bfr[4];
#pragma unroll
        for (int nt = 0; nt < 4; nt++)
            bfr[nt] = Bl[(ks * 8 + nh * 4 + nt) * 64 + lane];
#pragma unroll
        for (int mt = 0; mt < 4; mt++) {
            v8s a = Ap[mt][ks * 4 + quad];
#pragma unroll
            for (int nt = 0; nt < 4; nt++)
                acc[mt][nt] = __builtin_amdgcn_mfma_f32_16x16x32_bf16(a, bfr[nt], acc[mt][nt], 0, 0, 0);
        }
    }

#pragma unroll
    for (int mt = 0; mt < 4; mt++) {
#pragma unroll
        for (int r4 = 0; r4 < 4; r4++) {
            int row = base + mt * 16 + quad * 4 + r4;
            if (row < N) {
                short* orow = out + (size_t)row * HID + nh * 64;
#pragma unroll
                for (int nt = 0; nt < 4; nt++) {
                    float y = acc[mt][nt][r4] + pb[nt];
                    y = fmaxf(y, 0.f);
                    if (mode) y = ps[nt] * y + pt[nt];
                    orow[nt * 16 + m16] = f2bf(y);
                }
            }
        }
    }
}

// -------------------------------------------- mean pool per graph (batch sorted)
__global__ __launch_bounds__(512) void k_pool(const short* __restrict__ X,
                                              const int* __restrict__ batch,
                                              short* __restrict__ pooled) {
    int g = blockIdx.x;
    int tid = threadIdx.x;
    int col = tid & 127, part = tid >> 7;       // 4 partitions
    __shared__ int sh[2];
    __shared__ float red[512];
    if (tid < 2) {
        int target = g + tid;
        int lo = 0, hi = N_NODES;
        while (lo < hi) {
            int mid = (lo + hi) >> 1;
            if (batch[mid] < target) lo = mid + 1; else hi = mid;
        }
        sh[tid] = lo;
    }
    __syncthreads();
    int lo = sh[0], hi = sh[1];
    float s = 0.0f;
    for (int i = lo + part; i < hi; i += 4) {
        unsigned u = (unsigned)(unsigned short)X[(size_t)i * HID + col];
        s += __builtin_bit_cast(float, u << 16);
    }
    red[tid] = s;
    __syncthreads();
    if (part == 0) {
        float t = red[col] + red[col + 128] + red[col + 256] + red[col + 384];
        float cnt = (float)(hi - lo);
        pooled[g * HID + col] = f2bf(t / fmaxf(cnt, 1.0f));
    }
}

// -------------------------------------------- head: logits + log_softmax
__global__ __launch_bounds__(64) void k_final(const short* __restrict__ Hp,
                                              const float* __restrict__ W2,
                                              const float* __restrict__ b2,
                                              float* __restrict__ out) {
    int g = blockIdx.x;
    int lane = threadIdx.x;
    __shared__ float h[HID];
    {
        unsigned u0 = (unsigned)(unsigned short)Hp[g * HID + lane];
        unsigned u1 = (unsigned)(unsigned short)Hp[g * HID + lane + 64];
        h[lane]      = __builtin_bit_cast(float, u0 << 16);
        h[lane + 64] = __builtin_bit_cast(float, u1 << 16);
    }
    __syncthreads();
    float acc = 0.0f;
    if (lane < OUT_DIM) {
        for (int k = 0; k < HID; k++) acc += h[k] * W2[k * OUT_DIM + lane];
        acc += b2[lane];
    }
    float v = (lane < OUT_DIM) ? acc : -INFINITY;
    for (int d = 32; d > 0; d >>= 1) v = fmaxf(v, __shfl_xor(v, d, 64));
    float ex = (lane < OUT_DIM) ? expf(acc - v) : 0.0f;
    float s = ex;
    for (int d = 32; d > 0; d >>= 1) s += __shfl_xor(s, d, 64);
    if (lane < OUT_DIM) out[g * OUT_DIM + lane] = acc - v - logf(s);
}

// ----------------------------------------------------------------- launcher
extern "C" void kernel_launch(void* const* d_in, const int* in_sizes, int n_in,
                              void* d_out, int out_size, void* d_ws, size_t ws_size,
                              hipStream_t stream) {
    const float* x       = (const float*)d_in[0];
    const int*   edge    = (const int*)d_in[1];
    const int*   batch   = (const int*)d_in[2];
    const float* W1s     = (const float*)d_in[3];
    const float* b1s     = (const float*)d_in[4];
    const float* W2s     = (const float*)d_in[5];
    const float* b2s     = (const float*)d_in[6];
    const float* gammas  = (const float*)d_in[7];
    const float* betas   = (const float*)d_in[8];
    const float* bn_m    = (const float*)d_in[9];
    const float* bn_v    = (const float*)d_in[10];
    const float* eps_arr = (const float*)d_in[11];
    const float* lin1_W  = (const float*)d_in[12];
    const float* lin1_b  = (const float*)d_in[13];
    const float* lin2_W  = (const float*)d_in[14];
    const float* lin2_b  = (const float*)d_in[15];

    const int* src = edge;
    const int* dst = edge + N_EDGES;

    // workspace layout
    short* bufA    = (short*)d_ws;                        // 6.4M bf16
    short* bufB    = bufA + (size_t)N_NODES * HID;        // 6.4M bf16
    short* Wp      = bufB + (size_t)N_NODES * HID;        // 9*16384 bf16 (frag-packed)
    short* pooled  = Wp + 9 * 16384;                      // 128*128 bf16
    short* pooledH = pooled + N_GRAPHS * HID;             // 128*128 bf16
    int*   counts  = (int*)(pooledH + N_GRAPHS * HID);
    int*   offsets = counts + N_NODES;                    // N_NODES+1 (+pad)
    int*   cursor  = offsets + N_NODES + 16;
    int*   bsum    = cursor + N_NODES;
    int*   boff    = bsum + 256;
    int*   csr     = boff + 256;                          // 800000 int

    // ---- CSR build
    hipMemsetAsync(counts, 0, N_NODES * sizeof(int), stream);
    k_count<<<(N_EDGES + 255) / 256, 256, 0, stream>>>(dst, counts);
    k_red  <<<SCAN_BLKS, 256, 0, stream>>>(counts, bsum);
    k_scanB<<<1, 256, 0, stream>>>(bsum, boff, offsets);
    k_scan3<<<SCAN_BLKS, 256, 0, stream>>>(counts, boff, offsets, cursor);
    k_fill <<<(N_EDGES + 255) / 256, 256, 0, stream>>>(src, dst, cursor, csr);

    // ---- weight prep (bf16 frag-pack: W1s[0..3] -> slots 0-3, W2s -> 4-7, lin1 -> 8)
    k_prep<<<9, 256, 0, stream>>>(W1s, W2s, lin1_W, Wp);

    // ---- GIN layers
    const int aggBlocks = (N_NODES * 64 + 255) / 256;
    const int mmBlocks  = (N_NODES + 127) / 128;
    short* h = bufA;   // agg output / mm2 output
    short* t = bufB;   // mm1 output
    short* xb = nullptr;
    for (int l = 0; l < N_LAYERS; l++) {
        if (l == 0)
            k_agg_f32<<<aggBlocks, 256, 0, stream>>>(x, csr, offsets, h, eps_arr, 0);
        else
            k_agg_b16<<<aggBlocks, 256, 0, stream>>>(xb, csr, offsets, h, eps_arr, l);
        k_mm<<<mmBlocks, 256, 0, stream>>>(h, Wp + (size_t)l * 16384, b1s + l * HID,
                                           nullptr, nullptr, nullptr, nullptr,
                                           t, N_NODES, 0);
        k_mm<<<mmBlocks, 256, 0, stream>>>(t, Wp + (size_t)(4 + l) * 16384, b2s + l * HID,
                                           gammas + l * HID, betas + l * HID,
                                           bn_m + l * HID, bn_v + l * HID,
                                           h, N_NODES, 1);
        xb = h;
        short* tmp = h; h = t; t = tmp;
    }

    // ---- pool + head
    k_pool<<<N_GRAPHS, 512, 0, stream>>>(xb, batch, pooled);
    k_mm<<<1, 256, 0, stream>>>(pooled, Wp + (size_t)8 * 16384, lin1_b,
                                nullptr, nullptr, nullptr, nullptr,
                                pooledH, N_GRAPHS, 0);
    k_final<<<N_GRAPHS, 64, 0, stream>>>(pooledH, lin2_W, lin2_b, (float*)d_out);
}

// Round 3
// 467.239 us; speedup vs baseline: 3.0582x; 1.3813x over previous
//
#include <hip/hip_runtime.h>
#include <hip/hip_bf16.h>
#include <math.h>

#define N_NODES  50000
#define N_EDGES  800000
#define HID      128
#define OUT_DIM  40
#define N_LAYERS 4
#define N_GRAPHS 128
#define BN_EPS   1e-5f
#define SCAN_BLKS 196   // ceil(50000/256)
#define TROWS    64     // rows per k_mlp block
#define LSTRIDE  136    // LDS row stride in shorts (128 + 8 pad -> 2-way bank alias only)

typedef short v8s __attribute__((ext_vector_type(8)));
typedef float v4f __attribute__((ext_vector_type(4)));

static __device__ __forceinline__ short f2bf(float f) {
    __hip_bfloat16 h = __float2bfloat16(f);
    return __builtin_bit_cast(short, h);
}
static __device__ __forceinline__ float bflo(unsigned u) {
    return __builtin_bit_cast(float, u << 16);
}
static __device__ __forceinline__ float bfhi(unsigned u) {
    return __builtin_bit_cast(float, u & 0xffff0000u);
}
static __device__ __forceinline__ unsigned packbf(float a0, float a1) {
    return ((unsigned)(unsigned short)f2bf(a1) << 16) | (unsigned)(unsigned short)f2bf(a0);
}

// ---------------------------------------------------------------- CSR build
__global__ void k_count(const int* __restrict__ dst, int* __restrict__ counts) {
    int e = blockIdx.x * blockDim.x + threadIdx.x;
    if (e < N_EDGES) atomicAdd(&counts[dst[e]], 1);
}

__global__ __launch_bounds__(256) void k_red(const int* __restrict__ counts,
                                             int* __restrict__ bsum) {
    int i = blockIdx.x * 256 + threadIdx.x;
    int v = (i < N_NODES) ? counts[i] : 0;
    for (int d = 32; d > 0; d >>= 1) v += __shfl_down(v, d, 64);
    __shared__ int sh[4];
    if ((threadIdx.x & 63) == 0) sh[threadIdx.x >> 6] = v;
    __syncthreads();
    if (threadIdx.x == 0) bsum[blockIdx.x] = sh[0] + sh[1] + sh[2] + sh[3];
}

__global__ __launch_bounds__(256) void k_scanB(const int* __restrict__ bsum,
                                               int* __restrict__ boff,
                                               int* __restrict__ offsets) {
    __shared__ int sh[256];
    int t = threadIdx.x;
    int v = (t < SCAN_BLKS) ? bsum[t] : 0;
    sh[t] = v;
    __syncthreads();
    for (int d = 1; d < 256; d <<= 1) {
        int u = (t >= d) ? sh[t - d] : 0;
        __syncthreads();
        sh[t] += u;
        __syncthreads();
    }
    boff[t] = (t == 0) ? 0 : sh[t - 1];
    if (t == 255) offsets[N_NODES] = sh[255];
}

__global__ __launch_bounds__(256) void k_scan3(const int* __restrict__ counts,
                                               const int* __restrict__ boff,
                                               int* __restrict__ offsets,
                                               int* __restrict__ cursor) {
    __shared__ int sh[256];
    int t = threadIdx.x;
    int i = blockIdx.x * 256 + t;
    int c = (i < N_NODES) ? counts[i] : 0;
    sh[t] = c;
    __syncthreads();
    for (int d = 1; d < 256; d <<= 1) {
        int u = (t >= d) ? sh[t - d] : 0;
        __syncthreads();
        sh[t] += u;
        __syncthreads();
    }
    int excl = sh[t] - c + boff[blockIdx.x];
    if (i < N_NODES) { offsets[i] = excl; cursor[i] = excl; }
}

__global__ void k_fill(const int* __restrict__ src, const int* __restrict__ dst,
                       int* __restrict__ cursor, int* __restrict__ csr) {
    int e = blockIdx.x * blockDim.x + threadIdx.x;
    if (e < N_EDGES) {
        int p = atomicAdd(&cursor[dst[e]], 1);
        csr[p] = src[e];
    }
}

// --------------------------------------- weight prep: fp32 [K][N] -> bf16 frag-packed
// frag f = ks*8+nt (32 frags); chunk(f,lane) = 8 bf16 = B[k=ks*32+(lane>>4)*8+j][n=nt*16+(lane&15)]
__global__ __launch_bounds__(256) void k_prep(const float* __restrict__ W1s,
                                              const float* __restrict__ W2s,
                                              const float* __restrict__ lin1,
                                              short* __restrict__ Wp) {
    int b = blockIdx.x;   // 0..8
    const float* W = (b < 4) ? (W1s + b * 16384)
                   : (b < 8) ? (W2s + (b - 4) * 16384)
                             : lin1;
    short* o = Wp + (size_t)b * 16384;
    int t = threadIdx.x;
#pragma unroll
    for (int i = 0; i < 8; i++) {
        int c = i * 256 + t;            // chunk 0..2047
        int f = c >> 6, lane = c & 63;
        int ks = f >> 3, nt = f & 7;
        int k0 = ks * 32 + (lane >> 4) * 8;
        int n  = nt * 16 + (lane & 15);
        union { v8s v; short s[8]; } u;
#pragma unroll
        for (int j = 0; j < 8; j++) u.s[j] = f2bf(W[(k0 + j) * 128 + n]);
        *(v8s*)(o + (size_t)c * 8) = u.v;
    }
}

// --------------------------------------- x fp32 -> packed bf16
__global__ __launch_bounds__(256) void k_x2b(const float* __restrict__ x,
                                             unsigned* __restrict__ xb) {
    int i = blockIdx.x * 256 + threadIdx.x;   // over 50000*64
    if (i < N_NODES * 64) {
        float2 v = ((const float2*)x)[i];
        xb[i] = packbf(v.x, v.y);
    }
}

// --------------------------------------- fused layer: agg + mm1(relu) + mm2(relu+BN)
// block = 256 thr (4 waves), tile = 64 rows. Wave w: cols [w*32, w*32+32).
__global__ __launch_bounds__(256) void k_mlp(const short* __restrict__ xb,
                                             const int* __restrict__ csr,
                                             const int* __restrict__ off,
                                             const short* __restrict__ Wp1,
                                             const short* __restrict__ Wp2,
                                             const float* __restrict__ b1,
                                             const float* __restrict__ b2,
                                             const float* __restrict__ gamma,
                                             const float* __restrict__ beta,
                                             const float* __restrict__ mean,
                                             const float* __restrict__ var,
                                             const float* __restrict__ eps_arr,
                                             int layer,
                                             short* __restrict__ out,
                                             int N) {
    __shared__ short H[TROWS * LSTRIDE];      // 17408 B
    int tid = threadIdx.x, lane = tid & 63, w = tid >> 6;
    int m16 = lane & 15, quad = lane >> 4;
    int rbase = blockIdx.x * TROWS;

    // ---- phase 0: aggregate 64 rows into H (packed bf16 pairs, 4 gathers in flight)
    {
        float sc = 1.0f + eps_arr[layer];
        const unsigned* X = (const unsigned*)xb;
        unsigned* Hu = (unsigned*)H;
        for (int i = w; i < TROWS; i += 4) {
            int r = rbase + i;
            unsigned pk = 0;
            if (r < N) {
                int e0 = off[r], e1 = off[r + 1];
                unsigned su = X[(size_t)r * 64 + lane];
                float a0 = sc * bflo(su), a1 = sc * bfhi(su);
                for (int base = e0; base < e1; base += 64) {
                    int cnt = min(64, e1 - base);
                    int idx = (lane < cnt) ? csr[base + lane] : 0;
                    int j = 0;
                    for (; j + 4 <= cnt; j += 4) {
                        int s0 = __shfl(idx, j, 64);
                        int s1 = __shfl(idx, j + 1, 64);
                        int s2 = __shfl(idx, j + 2, 64);
                        int s3 = __shfl(idx, j + 3, 64);
                        unsigned u0 = X[(size_t)s0 * 64 + lane];
                        unsigned u1 = X[(size_t)s1 * 64 + lane];
                        unsigned u2 = X[(size_t)s2 * 64 + lane];
                        unsigned u3 = X[(size_t)s3 * 64 + lane];
                        a0 += bflo(u0) + bflo(u1) + bflo(u2) + bflo(u3);
                        a1 += bfhi(u0) + bfhi(u1) + bfhi(u2) + bfhi(u3);
                    }
                    for (; j < cnt; j++) {
                        int s = __shfl(idx, j, 64);
                        unsigned u = X[(size_t)s * 64 + lane];
                        a0 += bflo(u);
                        a1 += bfhi(u);
                    }
                }
                pk = packbf(a0, a1);
            }
            Hu[i * (LSTRIDE / 2) + lane] = pk;   // 2-way bank alias, free
        }
    }
    __syncthreads();

    // ---- per-wave epilogue params
    float pb1[2], pb2[2], ps[2], pt[2];
#pragma unroll
    for (int nt = 0; nt < 2; nt++) {
        int c = w * 32 + nt * 16 + m16;
        pb1[nt] = b1[c];
        pb2[nt] = b2[c];
        float g = gamma[c];
        float iv = rsqrtf(var[c] + BN_EPS);
        ps[nt] = g * iv;
        pt[nt] = beta[c] - g * mean[c] * iv;
    }

    // ---- phase 1: H1 = relu(agg @ W1 + b1); wave covers all 64 rows x its 32 cols
    v4f acc[4][2];
#pragma unroll
    for (int mt = 0; mt < 4; mt++)
#pragma unroll
        for (int nt = 0; nt < 2; nt++) acc[mt][nt] = {0.f, 0.f, 0.f, 0.f};

#pragma unroll
    for (int ks = 0; ks < 4; ks++) {
        v8s bfr[2];
#pragma unroll
        for (int nt = 0; nt < 2; nt++)
            bfr[nt] = ((const v8s*)Wp1)[(ks * 8 + w * 2 + nt) * 64 + lane];
#pragma unroll
        for (int mt = 0; mt < 4; mt++) {
            v8s a = *(const v8s*)&H[(mt * 16 + m16) * LSTRIDE + ks * 32 + quad * 8];
#pragma unroll
            for (int nt = 0; nt < 2; nt++)
                acc[mt][nt] = __builtin_amdgcn_mfma_f32_16x16x32_bf16(a, bfr[nt], acc[mt][nt], 0, 0, 0);
        }
    }
    __syncthreads();   // all reads of agg done

#pragma unroll
    for (int mt = 0; mt < 4; mt++)
#pragma unroll
        for (int nt = 0; nt < 2; nt++)
#pragma unroll
            for (int r4 = 0; r4 < 4; r4++) {
                float y = fmaxf(acc[mt][nt][r4] + pb1[nt], 0.f);
                H[(mt * 16 + quad * 4 + r4) * LSTRIDE + w * 32 + nt * 16 + m16] = f2bf(y);
            }
    __syncthreads();   // H1 complete

    // ---- phase 2: out = BN(relu(H1 @ W2 + b2))
    v4f acc2[4][2];
#pragma unroll
    for (int mt = 0; mt < 4; mt++)
#pragma unroll
        for (int nt = 0; nt < 2; nt++) acc2[mt][nt] = {0.f, 0.f, 0.f, 0.f};

#pragma unroll
    for (int ks = 0; ks < 4; ks++) {
        v8s bfr[2];
#pragma unroll
        for (int nt = 0; nt < 2; nt++)
            bfr[nt] = ((const v8s*)Wp2)[(ks * 8 + w * 2 + nt) * 64 + lane];
#pragma unroll
        for (int mt = 0; mt < 4; mt++) {
            v8s a = *(const v8s*)&H[(mt * 16 + m16) * LSTRIDE + ks * 32 + quad * 8];
#pragma unroll
            for (int nt = 0; nt < 2; nt++)
                acc2[mt][nt] = __builtin_amdgcn_mfma_f32_16x16x32_bf16(a, bfr[nt], acc2[mt][nt], 0, 0, 0);
        }
    }

#pragma unroll
    for (int mt = 0; mt < 4; mt++)
#pragma unroll
        for (int r4 = 0; r4 < 4; r4++) {
            int row = rbase + mt * 16 + quad * 4 + r4;
            if (row < N) {
#pragma unroll
                for (int nt = 0; nt < 2; nt++) {
                    float y = fmaxf(acc2[mt][nt][r4] + pb2[nt], 0.f);
                    y = ps[nt] * y + pt[nt];
                    out[(size_t)row * HID + w * 32 + nt * 16 + m16] = f2bf(y);
                }
            }
        }
}

// --------------------------------------------- MFMA GEMM (head lin1): 1 block, N<=128
__global__ __launch_bounds__(256) void k_mm(const short* __restrict__ A,
                                            const short* __restrict__ Wp,
                                            const float* __restrict__ bias,
                                            short* __restrict__ out, int N) {
    __shared__ short Wl[16384];
    int tid = threadIdx.x;
    {
        const v8s* s = (const v8s*)Wp;
        v8s* d = (v8s*)Wl;
#pragma unroll
        for (int i = 0; i < 8; i++) d[tid + i * 256] = s[tid + i * 256];
    }
    __syncthreads();

    int lane = tid & 63, w = tid >> 6;
    int m16 = lane & 15, quad = lane >> 4;
    int nh = w & 1, mh = w >> 1;
    int base = mh * 64;

    float pb[4];
#pragma unroll
    for (int nt = 0; nt < 4; nt++) pb[nt] = bias[nh * 64 + nt * 16 + m16];

    const v8s* Bl = (const v8s*)Wl;
    const v8s* Ap[4];
#pragma unroll
    for (int mt = 0; mt < 4; mt++) {
        int r = base + mt * 16 + m16;
        if (r >= N) r = 0;
        Ap[mt] = (const v8s*)(A + (size_t)r * HID);
    }

    v4f acc[4][4];
#pragma unroll
    for (int mt = 0; mt < 4; mt++)
#pragma unroll
        for (int nt = 0; nt < 4; nt++) acc[mt][nt] = {0.f, 0.f, 0.f, 0.f};

#pragma unroll
    for (int ks = 0; ks < 4; ks++) {
        v8s bfr[4];
#pragma unroll
        for (int nt = 0; nt < 4; nt++)
            bfr[nt] = Bl[(ks * 8 + nh * 4 + nt) * 64 + lane];
#pragma unroll
        for (int mt = 0; mt < 4; mt++) {
            v8s a = Ap[mt][ks * 4 + quad];
#pragma unroll
            for (int nt = 0; nt < 4; nt++)
                acc[mt][nt] = __builtin_amdgcn_mfma_f32_16x16x32_bf16(a, bfr[nt], acc[mt][nt], 0, 0, 0);
        }
    }

#pragma unroll
    for (int mt = 0; mt < 4; mt++)
#pragma unroll
        for (int r4 = 0; r4 < 4; r4++) {
            int row = base + mt * 16 + quad * 4 + r4;
            if (row < N) {
                short* orow = out + (size_t)row * HID + nh * 64;
#pragma unroll
                for (int nt = 0; nt < 4; nt++)
                    orow[nt * 16 + m16] = f2bf(fmaxf(acc[mt][nt][r4] + pb[nt], 0.f));
            }
        }
}

// -------------------------------------------- mean pool per graph (coalesced)
__global__ __launch_bounds__(256) void k_pool(const short* __restrict__ Xs,
                                              const int* __restrict__ batch,
                                              short* __restrict__ pooled) {
    int g = blockIdx.x;
    int tid = threadIdx.x, lane = tid & 63, w = tid >> 6;
    __shared__ int sh[2];
    __shared__ float red0[256], red1[256];
    if (tid < 2) {
        int target = g + tid;
        int lo = 0, hi = N_NODES;
        while (lo < hi) {
            int mid = (lo + hi) >> 1;
            if (batch[mid] < target) lo = mid + 1; else hi = mid;
        }
        sh[tid] = lo;
    }
    __syncthreads();
    int lo = sh[0], hi = sh[1];
    const unsigned* X = (const unsigned*)Xs;
    float a0 = 0.f, a1 = 0.f;
    for (int r = lo + w; r < hi; r += 4) {
        unsigned u = X[(size_t)r * 64 + lane];
        a0 += bflo(u);
        a1 += bfhi(u);
    }
    red0[tid] = a0;
    red1[tid] = a1;
    __syncthreads();
    if (w == 0) {
        float s0 = red0[lane] + red0[64 + lane] + red0[128 + lane] + red0[192 + lane];
        float s1 = red1[lane] + red1[64 + lane] + red1[128 + lane] + red1[192 + lane];
        float c = fmaxf((float)(hi - lo), 1.0f);
        ((unsigned*)pooled)[g * 64 + lane] = packbf(s0 / c, s1 / c);
    }
}

// -------------------------------------------- head: logits + log_softmax
__global__ __launch_bounds__(64) void k_final(const short* __restrict__ Hp,
                                              const float* __restrict__ W2,
                                              const float* __restrict__ b2,
                                              float* __restrict__ out) {
    int g = blockIdx.x;
    int lane = threadIdx.x;
    __shared__ float h[HID];
    {
        unsigned u0 = (unsigned)(unsigned short)Hp[g * HID + lane];
        unsigned u1 = (unsigned)(unsigned short)Hp[g * HID + lane + 64];
        h[lane]      = __builtin_bit_cast(float, u0 << 16);
        h[lane + 64] = __builtin_bit_cast(float, u1 << 16);
    }
    __syncthreads();
    float acc = 0.0f;
    if (lane < OUT_DIM) {
        for (int k = 0; k < HID; k++) acc += h[k] * W2[k * OUT_DIM + lane];
        acc += b2[lane];
    }
    float v = (lane < OUT_DIM) ? acc : -INFINITY;
    for (int d = 32; d > 0; d >>= 1) v = fmaxf(v, __shfl_xor(v, d, 64));
    float ex = (lane < OUT_DIM) ? expf(acc - v) : 0.0f;
    float s = ex;
    for (int d = 32; d > 0; d >>= 1) s += __shfl_xor(s, d, 64);
    if (lane < OUT_DIM) out[g * OUT_DIM + lane] = acc - v - logf(s);
}

// ----------------------------------------------------------------- launcher
extern "C" void kernel_launch(void* const* d_in, const int* in_sizes, int n_in,
                              void* d_out, int out_size, void* d_ws, size_t ws_size,
                              hipStream_t stream) {
    const float* x       = (const float*)d_in[0];
    const int*   edge    = (const int*)d_in[1];
    const int*   batch   = (const int*)d_in[2];
    const float* W1s     = (const float*)d_in[3];
    const float* b1s     = (const float*)d_in[4];
    const float* W2s     = (const float*)d_in[5];
    const float* b2s     = (const float*)d_in[6];
    const float* gammas  = (const float*)d_in[7];
    const float* betas   = (const float*)d_in[8];
    const float* bn_m    = (const float*)d_in[9];
    const float* bn_v    = (const float*)d_in[10];
    const float* eps_arr = (const float*)d_in[11];
    const float* lin1_W  = (const float*)d_in[12];
    const float* lin1_b  = (const float*)d_in[13];
    const float* lin2_W  = (const float*)d_in[14];
    const float* lin2_b  = (const float*)d_in[15];

    const int* src = edge;
    const int* dst = edge + N_EDGES;

    // workspace layout
    short* bufA    = (short*)d_ws;                        // 6.4M bf16
    short* bufB    = bufA + (size_t)N_NODES * HID;        // 6.4M bf16
    short* Wp      = bufB + (size_t)N_NODES * HID;        // 9*16384 bf16
    short* pooled  = Wp + 9 * 16384;
    short* pooledH = pooled + N_GRAPHS * HID;
    int*   counts  = (int*)(pooledH + N_GRAPHS * HID);
    int*   offsets = counts + N_NODES;                    // N_NODES+1 (+pad)
    int*   cursor  = offsets + N_NODES + 16;
    int*   bsum    = cursor + N_NODES;
    int*   boff    = bsum + 256;
    int*   csr     = boff + 256;                          // 800000 int

    // ---- CSR build
    hipMemsetAsync(counts, 0, N_NODES * sizeof(int), stream);
    k_count<<<(N_EDGES + 255) / 256, 256, 0, stream>>>(dst, counts);
    k_red  <<<SCAN_BLKS, 256, 0, stream>>>(counts, bsum);
    k_scanB<<<1, 256, 0, stream>>>(bsum, boff, offsets);
    k_scan3<<<SCAN_BLKS, 256, 0, stream>>>(counts, boff, offsets, cursor);
    k_fill <<<(N_EDGES + 255) / 256, 256, 0, stream>>>(src, dst, cursor, csr);

    // ---- weight prep + x conversion
    k_prep<<<9, 256, 0, stream>>>(W1s, W2s, lin1_W, Wp);
    k_x2b<<<(N_NODES * 64 + 255) / 256, 256, 0, stream>>>(x, (unsigned*)bufA);

    // ---- fused GIN layers (in/out ping-pong; layer 0 reads converted x in bufA)
    const int mlpBlocks = (N_NODES + TROWS - 1) / TROWS;   // 782
    short* in  = bufA;
    short* outb = bufB;
    for (int l = 0; l < N_LAYERS; l++) {
        k_mlp<<<mlpBlocks, 256, 0, stream>>>(in, csr, offsets,
                                             Wp + (size_t)l * 16384,
                                             Wp + (size_t)(4 + l) * 16384,
                                             b1s + l * HID, b2s + l * HID,
                                             gammas + l * HID, betas + l * HID,
                                             bn_m + l * HID, bn_v + l * HID,
                                             eps_arr, l, outb, N_NODES);
        short* tmp = in; in = outb; outb = tmp;
    }
    // final features now in `in`

    // ---- pool + head
    k_pool<<<N_GRAPHS, 256, 0, stream>>>(in, batch, pooled);
    k_mm<<<1, 256, 0, stream>>>(pooled, Wp + (size_t)8 * 16384, lin1_b, pooledH, N_GRAPHS);
    k_final<<<N_GRAPHS, 64, 0, stream>>>(pooledH, lin2_W, lin2_b, (float*)d_out);
}